// Round 12
// baseline (2712.851 us; speedup 1.0000x reference)
//
#include <hip/hip_runtime.h>
#include <hip/hip_cooperative_groups.h>

namespace cgx = cooperative_groups;

static constexpr int NN  = 6144;
static constexpr int NE  = 98304;
static constexpr int NF  = 128;
static constexpr int NT  = 16;
static constexpr int MN  = 10;
static constexpr int NCG = 5;
static constexpr int NSK = 50;
static constexpr int WPR = NN / 32;
static constexpr int TPB = 768;
static constexpr int NBLK = 256;
static constexpr int G   = 8;            // blocks per template; 1 row/thread
static constexpr int NW  = TPB / 64;     // 12 waves

static_assert(G * TPB == NN, "row mapping");

// workspace layout (float elements); BM (setup-only) aliases T4..DD4 region
static constexpr size_t OFF_M   = 0;                                // fp32 [NT][NN][10]
static constexpr size_t OFF_T4  = OFF_M   + (size_t)NT * NN * MN;   // uint4 [NT][NN] (bf16 cols0-7)
static constexpr size_t OFF_T1  = OFF_T4  + (size_t)NT * NN * 4;    // u32   [NT][NN] (cols8-9)
static constexpr size_t OFF_C4  = OFF_T1  + (size_t)NT * NN;
static constexpr size_t OFF_C1  = OFF_C4  + (size_t)NT * NN * 4;
static constexpr size_t OFF_D4  = OFF_C1  + (size_t)NT * NN;
static constexpr size_t OFF_D1  = OFF_D4  + (size_t)NT * NN * 4;
static constexpr size_t OFF_DD4 = OFF_D1  + (size_t)NT * NN;        // dd planes (gathered)
static constexpr size_t OFF_DD1 = OFF_DD4 + (size_t)NT * NN * 4;
static constexpr size_t OFF_RS  = OFF_DD1 + (size_t)NT * NN;
static constexpr size_t OFF_DEG = OFF_RS  + NN;
static constexpr size_t OFF_CI  = OFF_DEG + NN;                     // ushort[2*NE]
static constexpr size_t OFF_NNZ = OFF_CI  + NE;
static constexpr size_t OFF_SL  = OFF_NNZ + 16;                     // u64 [NT][G][8] stamped slots

static constexpr int LDS_SP  = TPB * 7 * 4;   // 21504 B packed partials (stride 7)
static constexpr int LDS_DYN = 86016;         // oversize: forces 1 block/CU

__device__ __forceinline__ unsigned f2bf(float f) {
    unsigned u = __float_as_uint(f);
    return (u + 0x7fffu + ((u >> 16) & 1u)) >> 16;
}
__device__ __forceinline__ unsigned packbf(float a, float b) { return f2bf(a) | (f2bf(b) << 16); }
__device__ __forceinline__ float bflo(unsigned w) { return __uint_as_float(w << 16); }
__device__ __forceinline__ float bfhi(unsigned w) { return __uint_as_float(w & 0xffff0000u); }

__device__ __forceinline__ void slput(unsigned long long* p, unsigned st, unsigned pay) {
    __hip_atomic_store(p, ((unsigned long long)st << 32) | (unsigned long long)pay,
                       __ATOMIC_RELEASE, __HIP_MEMORY_SCOPE_AGENT);
}
__device__ __forceinline__ unsigned slpoll(const unsigned long long* p, unsigned st) {
    unsigned long long v;
    do { v = __hip_atomic_load(p, __ATOMIC_ACQUIRE, __HIP_MEMORY_SCOPE_AGENT); }
    while ((unsigned)(v >> 32) != st);
    return (unsigned)v;
}
__device__ __forceinline__ unsigned slget(const unsigned long long* p) {
    return (unsigned)__hip_atomic_load(p, __ATOMIC_RELAXED, __HIP_MEMORY_SCOPE_AGENT);
}

extern __shared__ char sMem[];

__global__ __launch_bounds__(TPB) void tfgw_kernel(
    const float* __restrict__ x, const void* __restrict__ eiv,
    const float* __restrict__ tpl, const float* __restrict__ tf,
    const float* __restrict__ q0, const float* __restrict__ a0,
    float* __restrict__ out, float* __restrict__ W)
{
    __shared__ float sC2[MN * MN];
    __shared__ float sq[MN], scq[MN], sqC2[MN], sNSQ[MN];
    __shared__ __align__(16) float sv[12];
    __shared__ float sRed[3 * NW];
    __shared__ float sBC[2];

    const int tid = threadIdx.x;
    const int bid = blockIdx.x;

    unsigned* BM    = (unsigned*)(W + OFF_T4);   // aliased; dead after setup
    int* rowst      = (int*)(W + OFF_RS);
    int* degi       = (int*)(W + OFF_DEG);
    unsigned short* colix = (unsigned short*)(W + OFF_CI);
    int* nnzc       = (int*)(W + OFF_NNZ);
    float* Mw  = W + OFF_M;
    unsigned long long* SL = (unsigned long long*)(W + OFF_SL);

    unsigned* sPp = (unsigned*)sMem;             // [TPB*7]

    const float alpha  = 1.f / (1.f + __expf(-a0[0]));
    const float invn   = 1.f / (float)NN;
    const float alpha2 = 2.f * alpha;
    const float oma    = 1.f - alpha;

    cgx::grid_group grid = cgx::this_grid();

    // ---- P0: zero bitmap + nnz + sync slots ----
    for (int idx = bid * TPB + tid; idx < NN * WPR; idx += NBLK * TPB) BM[idx] = 0u;
    for (int idx = bid * TPB + tid; idx < NT * G * 8 * 2; idx += NBLK * TPB)
        ((unsigned*)SL)[idx] = 0u;
    if (bid == 0 && tid == 0) *nnzc = 0;
    grid.sync();

    // ---- P1: adjacency bits + feature cost M (sTF overlays sMem) ----
    {
        const unsigned* uw = (const unsigned*)eiv;
        const bool is64 = (uw[1] == 0u && uw[3] == 0u && uw[5] == 0u);
        for (int e = bid * TPB + tid; e < NE; e += NBLK * TPB) {
            int s, d;
            if (is64) {
                s = (int)((const long long*)eiv)[e];
                d = (int)((const long long*)eiv)[NE + e];
            } else {
                s = ((const int*)eiv)[e];
                d = ((const int*)eiv)[NE + e];
            }
            atomicOr(&BM[(size_t)s * WPR + (d >> 5)], 1u << (d & 31));
            atomicOr(&BM[(size_t)d * WPR + (s >> 5)], 1u << (s & 31));
        }
        float* sTF = (float*)sMem;
        const int tt = bid >> 4, rb = bid & 15;
        for (int k = tid; k < MN * NF; k += TPB) sTF[k] = tf[tt * MN * NF + k];
        __syncthreads();
        if (tid < MN) {
            float s = 0.f;
            for (int k = 0; k < NF; ++k) { float v = sTF[tid * NF + k]; s += v * v; }
            sNSQ[tid] = s;
        }
        __syncthreads();
        if (tid < 384) {
            const int i = rb * 384 + tid;
            const float4* x4 = (const float4*)(x + (size_t)i * NF);
            const float4* t4 = (const float4*)sTF;
            float acc[MN]; float xn = 0.f;
            #pragma unroll
            for (int j = 0; j < MN; ++j) acc[j] = 0.f;
            for (int k4 = 0; k4 < NF / 4; ++k4) {
                float4 xv = x4[k4];
                xn += xv.x * xv.x + xv.y * xv.y + xv.z * xv.z + xv.w * xv.w;
                #pragma unroll
                for (int j = 0; j < MN; ++j) {
                    float4 tv = t4[j * (NF / 4) + k4];
                    acc[j] += xv.x * tv.x + xv.y * tv.y + xv.z * tv.z + xv.w * tv.w;
                }
            }
            float* Mrow = Mw + (size_t)tt * NN * MN + (size_t)i * MN;
            #pragma unroll
            for (int j = 0; j < MN; ++j) Mrow[j] = xn + sNSQ[j] - 2.f * acc[j];
        }
    }
    grid.sync();

    // ---- P2: degrees + CSR (ushort cols) ----
    {
        const int i = bid * TPB + tid;
        if (i < NN) {
            int cnt = 0;
            for (int w = 0; w < WPR; ++w) cnt += __popc(BM[(size_t)i * WPR + w]);
            int st0 = atomicAdd(nnzc, cnt);
            rowst[i] = st0; degi[i] = cnt;
            int p = st0;
            for (int w = 0; w < WPR; ++w) {
                unsigned m = BM[(size_t)i * WPR + w];
                while (m) { int b = __ffs(m) - 1; m &= m - 1; colix[p++] = (unsigned short)((w << 5) + b); }
            }
        }
    }
    grid.sync();     // last grid sync

    if (bid >= NT * G) return;

    // ================= template t, slice g: thread owns global row r =================
    const int t = bid & 15;
    const int g = bid >> 4;
    const int r = g * TPB + tid;
    unsigned long long* SLt = SL + (size_t)t * G * 8;   // [G][8]
    unsigned long long* SLg = SLt + (size_t)g * 8;

    uint4*    Tb4 = (uint4*)(W + OFF_T4) + (size_t)t * NN;
    unsigned* Tb1 = (unsigned*)(W + OFF_T1) + (size_t)t * NN;
    uint4*    Cb4 = (uint4*)(W + OFF_C4) + (size_t)t * NN;
    unsigned* Cb1 = (unsigned*)(W + OFF_C1) + (size_t)t * NN;
    uint4*    Db4 = (uint4*)(W + OFF_D4) + (size_t)t * NN;
    unsigned* Db1 = (unsigned*)(W + OFF_D1) + (size_t)t * NN;
    uint4*    DD4 = (uint4*)(W + OFF_DD4) + (size_t)t * NN;
    unsigned* DD1 = (unsigned*)(W + OFF_DD1) + (size_t)t * NN;
    const float* Mb = Mw + (size_t)t * NN * MN;

    if (tid == 0) {
        float qv[MN]; float qm = -1e30f;
        for (int j = 0; j < MN; ++j) { qv[j] = q0[t * MN + j]; qm = fmaxf(qm, qv[j]); }
        float qs = 0.f;
        for (int j = 0; j < MN; ++j) { qv[j] = __expf(qv[j] - qm); qs += qv[j]; }
        for (int j = 0; j < MN; ++j) { qv[j] /= qs; sq[j] = qv[j]; }
        for (int j = 0; j < MN; ++j) {
            float s2 = 0.f, s1 = 0.f;
            for (int k = 0; k < MN; ++k) {
                float cjk = tpl[t * MN * MN + j * MN + k];
                s2 += cjk * cjk * qv[k];
                s1 += tpl[t * MN * MN + k * MN + j] * qv[k];
            }
            scq[j] = s2; sqC2[j] = s1;
        }
    }
    for (int k = tid; k < MN * MN; k += TPB) sC2[k] = tpl[t * MN * MN + k];
    __syncthreads();

    const float cp = (float)degi[r] * invn;
    const int rst = rowst[r], rdg = degi[r];

    unsigned st = 0;            // barrier stamp (identical sequence on all blocks)
    float e[MN];                // E row (fp32, registers)
    float dd[MN];               // dT row (fp32, registers; persists CG->CG)
    #pragma unroll
    for (int j = 0; j < MN; ++j) { e[j] = 0.f; dd[j] = 0.f; }

    // one Sinkhorn barrier round: block-reduce a[10] -> cross-block sum -> sv
    auto sink_round = [&](const float* a) {
        #pragma unroll
        for (int p = 0; p < 5; ++p) sPp[tid * 7 + p] = packbf(a[2*p], a[2*p+1]);
        __syncthreads();
        float s0 = 0.f, s1 = 0.f;
        if (tid < 320) {
            const int p = tid >> 6, c = tid & 63;
            #pragma unroll
            for (int kk = 0; kk < NW; ++kk) {
                unsigned w = sPp[(c + (kk << 6)) * 7 + p];
                s0 += bflo(w); s1 += bfhi(w);
            }
            #pragma unroll
            for (int d = 32; d; d >>= 1) { s0 += __shfl_xor(s0, d); s1 += __shfl_xor(s1, d); }
        }
        ++st;
        if (tid < 320 && (tid & 63) == 0) slput(SLg + (tid >> 6), st, packbf(s0, s1));
        if (tid < 40) {
            const int pp = tid >> 3, gg = tid & 7;
            unsigned pay = slpoll(SLt + gg * 8 + pp, st);
            float f0 = bflo(pay), f1 = bfhi(pay);
            f0 += __shfl_xor(f0, 1); f0 += __shfl_xor(f0, 2); f0 += __shfl_xor(f0, 4);
            f1 += __shfl_xor(f1, 1); f1 += __shfl_xor(f1, 2); f1 += __shfl_xor(f1, 4);
            if (gg == 0) { sv[2*pp] = sq[2*pp] / f0; sv[2*pp+1] = sq[2*pp+1] / f1; }
        }
        __syncthreads();
    };

    for (int cgi = 0; cgi < NCG; ++cgi) {
        // ---- tau from previous CG's dots (slots 0-2 @ st-1, slot 3 @ st) ----
        float tau = 0.f;
        if (cgi > 0) {
            if (tid < G) {
                float a3 = __uint_as_float(slpoll(SLt + tid * 8 + 3, st));
                float a0v = __uint_as_float(slget(SLt + tid * 8 + 0));
                float a1v = __uint_as_float(slget(SLt + tid * 8 + 1));
                float a2v = __uint_as_float(slget(SLt + tid * 8 + 2));
                #pragma unroll
                for (int d = 1; d < 8; d <<= 1) {
                    a0v += __shfl_xor(a0v, d); a1v += __shfl_xor(a1v, d);
                    a2v += __shfl_xor(a2v, d); a3  += __shfl_xor(a3, d);
                }
                if (tid == 0) {
                    float aq = -2.f * alpha * a3;
                    float bq = oma * a0v + alpha * (a1v - 4.f * a2v);
                    float tv;
                    if (aq > 0.f) tv = fminf(fmaxf(-bq / (2.f * aq + 1e-16f), 0.f), 1.f);
                    else          tv = (aq + bq < 0.f) ? 1.f : 0.f;
                    sBC[0] = tv;
                }
            }
            __syncthreads();
            tau = sBC[0];
            if (tau == 0.f) break;          // identical on all blocks
        }

        // ---- Phase A: update T,C (own row); graw -> e later ----
        float graw[MN];
        {
            float C[MN];
            if (cgi == 0) {
                uint4 tw4; unsigned tw1; uint4 cw4; unsigned cw1;
                tw4.x = packbf(sq[0]*invn, sq[1]*invn); tw4.y = packbf(sq[2]*invn, sq[3]*invn);
                tw4.z = packbf(sq[4]*invn, sq[5]*invn); tw4.w = packbf(sq[6]*invn, sq[7]*invn);
                tw1   = packbf(sq[8]*invn, sq[9]*invn);
                cw4.x = packbf(cp*sqC2[0], cp*sqC2[1]); cw4.y = packbf(cp*sqC2[2], cp*sqC2[3]);
                cw4.z = packbf(cp*sqC2[4], cp*sqC2[5]); cw4.w = packbf(cp*sqC2[6], cp*sqC2[7]);
                cw1   = packbf(cp*sqC2[8], cp*sqC2[9]);
                Tb4[r] = tw4; Tb1[r] = tw1; Cb4[r] = cw4; Cb1[r] = cw1;
                C[0]=bflo(cw4.x); C[1]=bfhi(cw4.x); C[2]=bflo(cw4.y); C[3]=bfhi(cw4.y);
                C[4]=bflo(cw4.z); C[5]=bfhi(cw4.z); C[6]=bflo(cw4.w); C[7]=bfhi(cw4.w);
                C[8]=bflo(cw1);   C[9]=bfhi(cw1);
            } else {
                uint4 tw4 = Tb4[r]; unsigned tw1 = Tb1[r];
                uint4 cw4 = Cb4[r]; unsigned cw1 = Cb1[r];
                uint4 Dw4 = Db4[r]; unsigned Dw1 = Db1[r];
                float T[MN], Dd[MN];
                T[0]=bflo(tw4.x); T[1]=bfhi(tw4.x); T[2]=bflo(tw4.y); T[3]=bfhi(tw4.y);
                T[4]=bflo(tw4.z); T[5]=bfhi(tw4.z); T[6]=bflo(tw4.w); T[7]=bfhi(tw4.w);
                T[8]=bflo(tw1);   T[9]=bfhi(tw1);
                C[0]=bflo(cw4.x); C[1]=bfhi(cw4.x); C[2]=bflo(cw4.y); C[3]=bfhi(cw4.y);
                C[4]=bflo(cw4.z); C[5]=bfhi(cw4.z); C[6]=bflo(cw4.w); C[7]=bfhi(cw4.w);
                C[8]=bflo(cw1);   C[9]=bfhi(cw1);
                Dd[0]=bflo(Dw4.x); Dd[1]=bfhi(Dw4.x); Dd[2]=bflo(Dw4.y); Dd[3]=bfhi(Dw4.y);
                Dd[4]=bflo(Dw4.z); Dd[5]=bfhi(Dw4.z); Dd[6]=bflo(Dw4.w); Dd[7]=bfhi(Dw4.w);
                Dd[8]=bflo(Dw1);   Dd[9]=bfhi(Dw1);
                #pragma unroll
                for (int j = 0; j < MN; ++j) { T[j] += tau * dd[j]; C[j] += tau * Dd[j]; }
                uint4 n4; unsigned n1;
                n4.x = packbf(T[0],T[1]); n4.y = packbf(T[2],T[3]);
                n4.z = packbf(T[4],T[5]); n4.w = packbf(T[6],T[7]); n1 = packbf(T[8],T[9]);
                Tb4[r] = n4; Tb1[r] = n1;
                n4.x = packbf(C[0],C[1]); n4.y = packbf(C[2],C[3]);
                n4.z = packbf(C[4],C[5]); n4.w = packbf(C[6],C[7]); n1 = packbf(C[8],C[9]);
                Cb4[r] = n4; Cb1[r] = n1;
                C[0]=bflo(n4.x); C[1]=bfhi(n4.x); C[2]=bflo(n4.y); C[3]=bfhi(n4.y);
                C[4]=bflo(n4.z); C[5]=bfhi(n4.z); C[6]=bflo(n4.w); C[7]=bfhi(n4.w);
                C[8]=bflo(n1);   C[9]=bfhi(n1);
            }
            float gmax = 0.f;
            #pragma unroll
            for (int h = 0; h < 5; ++h) {
                float2 mv = *(const float2*)(Mb + (size_t)r * MN + 2*h);
                graw[2*h]   = oma * mv.x + alpha2 * (cp + scq[2*h]   - 2.f * C[2*h]);
                graw[2*h+1] = oma * mv.y + alpha2 * (cp + scq[2*h+1] - 2.f * C[2*h+1]);
                gmax = fmaxf(gmax, fmaxf(__builtin_fabsf(graw[2*h]), __builtin_fabsf(graw[2*h+1])));
            }
            // gmax barrier
            #pragma unroll
            for (int d = 32; d; d >>= 1) gmax = fmaxf(gmax, __shfl_xor(gmax, d));
            if ((tid & 63) == 0) sRed[tid >> 6] = gmax;
            __syncthreads();
            ++st;
            if (tid == 0) {
                float m = sRed[0];
                for (int w = 1; w < NW; ++w) m = fmaxf(m, sRed[w]);
                slput(SLg + 6, st, __float_as_uint(m));
            }
            if (tid < G) {
                float mg = __uint_as_float(slpoll(SLt + tid * 8 + 6, st));
                mg = fmaxf(mg, __shfl_xor(mg, 1));
                mg = fmaxf(mg, __shfl_xor(mg, 2));
                mg = fmaxf(mg, __shfl_xor(mg, 4));
                if (tid == 0) sBC[1] = 1.f / (0.05f * mg + 1e-8f);
            }
            __syncthreads();
        }
        const float invreg = sBC[1];
        #pragma unroll
        for (int j = 0; j < MN; ++j) e[j] = __expf(-graw[j] * invreg);

        // ---- Sinkhorn: (cgi==0: u=1 init round) + 50 fused rounds; warm-started v ----
        if (cgi == 0) sink_round(e);
        for (int it = 0; it < NSK; ++it) {
            float vv[MN];
            {
                const float4* s4 = (const float4*)sv;
                float4 v0 = s4[0], v1 = s4[1]; float2 v2 = *(const float2*)(sv + 8);
                vv[0]=v0.x; vv[1]=v0.y; vv[2]=v0.z; vv[3]=v0.w;
                vv[4]=v1.x; vv[5]=v1.y; vv[6]=v1.z; vv[7]=v1.w;
                vv[8]=v2.x; vv[9]=v2.y;
            }
            float R = 0.f;
            #pragma unroll
            for (int j = 0; j < MN; ++j) R += e[j] * vv[j];
            const float u = invn * __builtin_amdgcn_rcpf(R);
            float a[MN];
            #pragma unroll
            for (int j = 0; j < MN; ++j) a[j] = e[j] * u;
            sink_round(a);
        }

        // ---- dT phase: dd = u e v - T (own row); dots; dd -> global planes ----
        {
            float vv[MN];
            {
                const float4* s4 = (const float4*)sv;
                float4 v0 = s4[0], v1 = s4[1]; float2 v2 = *(const float2*)(sv + 8);
                vv[0]=v0.x; vv[1]=v0.y; vv[2]=v0.z; vv[3]=v0.w;
                vv[4]=v1.x; vv[5]=v1.y; vv[6]=v1.z; vv[7]=v1.w;
                vv[8]=v2.x; vv[9]=v2.y;
            }
            float R = 0.f;
            #pragma unroll
            for (int j = 0; j < MN; ++j) R += e[j] * vv[j];
            const float u = invn * __builtin_amdgcn_rcpf(R);
            uint4 tw4 = Tb4[r]; unsigned tw1 = Tb1[r];
            uint4 cw4 = Cb4[r]; unsigned cw1 = Cb1[r];
            float T[MN], C[MN];
            T[0]=bflo(tw4.x); T[1]=bfhi(tw4.x); T[2]=bflo(tw4.y); T[3]=bfhi(tw4.y);
            T[4]=bflo(tw4.z); T[5]=bfhi(tw4.z); T[6]=bflo(tw4.w); T[7]=bfhi(tw4.w);
            T[8]=bflo(tw1);   T[9]=bfhi(tw1);
            C[0]=bflo(cw4.x); C[1]=bfhi(cw4.x); C[2]=bflo(cw4.y); C[3]=bfhi(cw4.y);
            C[4]=bflo(cw4.z); C[5]=bfhi(cw4.z); C[6]=bflo(cw4.w); C[7]=bfhi(cw4.w);
            C[8]=bflo(cw1);   C[9]=bfhi(cw1);
            float sMdT = 0.f, sCdT = 0.f, sCTdT = 0.f;
            #pragma unroll
            for (int h = 0; h < 5; ++h) {
                float2 mv = *(const float2*)(Mb + (size_t)r * MN + 2*h);
                float d0 = u * e[2*h]   * vv[2*h]   - T[2*h];
                float d1 = u * e[2*h+1] * vv[2*h+1] - T[2*h+1];
                dd[2*h] = d0; dd[2*h+1] = d1;
                sMdT  += mv.x * d0 + mv.y * d1;
                sCdT  += (cp + scq[2*h]) * d0 + (cp + scq[2*h+1]) * d1;
                sCTdT += C[2*h] * d0 + C[2*h+1] * d1;
            }
            DD4[r] = make_uint4(packbf(dd[0],dd[1]), packbf(dd[2],dd[3]),
                                packbf(dd[4],dd[5]), packbf(dd[6],dd[7]));
            DD1[r] = packbf(dd[8], dd[9]);
            #pragma unroll
            for (int d = 32; d; d >>= 1) {
                sMdT  += __shfl_xor(sMdT, d);
                sCdT  += __shfl_xor(sCdT, d);
                sCTdT += __shfl_xor(sCTdT, d);
            }
            if ((tid & 63) == 0) {
                const int w = tid >> 6;
                sRed[w] = sMdT; sRed[NW + w] = sCdT; sRed[2*NW + w] = sCTdT;
            }
            __syncthreads();                 // dd stores drained; sRed staged
            ++st;
            if (tid == 0) {
                float r0 = 0.f, r1 = 0.f, r2 = 0.f;
                for (int w = 0; w < NW; ++w) { r0 += sRed[w]; r1 += sRed[NW+w]; r2 += sRed[2*NW+w]; }
                __threadfence();             // release dd (L2 writeback)
                slput(SLg + 0, st, __float_as_uint(r0));
                slput(SLg + 1, st, __float_as_uint(r1));
                slput(SLg + 2, st, __float_as_uint(r2));
                slput(SLg + 7, st, 0u);
            }
            if (tid < G) (void)slpoll(SLt + tid * 8 + 7, st);
            __syncthreads();
            if (tid == 0) __threadfence();   // acquire dd (invalidate stale L1/L2)
            __syncthreads();
        }

        // ---- SpMM: y = sum_{j in N(r)} dd_j (global gather); D own row; sA dot ----
        {
            float y[MN];
            #pragma unroll
            for (int j = 0; j < MN; ++j) y[j] = 0.f;
            const unsigned short* cl = colix + rst;
            for (int e2 = 0; e2 < rdg; ++e2) {
                const int j = cl[e2];
                uint4 q = DD4[j]; unsigned b4 = DD1[j];
                y[0] += bflo(q.x); y[1] += bfhi(q.x);
                y[2] += bflo(q.y); y[3] += bfhi(q.y);
                y[4] += bflo(q.z); y[5] += bfhi(q.z);
                y[6] += bflo(q.w); y[7] += bfhi(q.w);
                y[8] += bflo(b4);  y[9] += bfhi(b4);
            }
            float o[MN]; float dot = 0.f;
            #pragma unroll
            for (int h = 0; h < 5; ++h) {
                float o0 = 0.f, o1 = 0.f;
                #pragma unroll
                for (int j = 0; j < MN; ++j) {
                    o0 += y[j] * sC2[j * MN + 2*h];
                    o1 += y[j] * sC2[j * MN + 2*h + 1];
                }
                o[2*h] = o0; o[2*h+1] = o1;
                dot += o0 * dd[2*h] + o1 * dd[2*h+1];
            }
            Db4[r] = make_uint4(packbf(o[0],o[1]), packbf(o[2],o[3]),
                                packbf(o[4],o[5]), packbf(o[6],o[7]));
            Db1[r] = packbf(o[8], o[9]);
            #pragma unroll
            for (int d = 32; d; d >>= 1) dot += __shfl_xor(dot, d);
            if ((tid & 63) == 0) sRed[tid >> 6] = dot;
            __syncthreads();
            ++st;
            if (tid == 0) {
                float s = 0.f;
                for (int w = 0; w < NW; ++w) s += sRed[w];
                slput(SLg + 3, st, __float_as_uint(s));
            }
            // no poll here: consumed at next CG top / F
        }
    }

    // ---- F: final tau (from last dots) + objective ----
    {
        if (tid < G) {
            float a3 = __uint_as_float(slpoll(SLt + tid * 8 + 3, st));
            float a0v = __uint_as_float(slget(SLt + tid * 8 + 0));
            float a1v = __uint_as_float(slget(SLt + tid * 8 + 1));
            float a2v = __uint_as_float(slget(SLt + tid * 8 + 2));
            #pragma unroll
            for (int d = 1; d < 8; d <<= 1) {
                a0v += __shfl_xor(a0v, d); a1v += __shfl_xor(a1v, d);
                a2v += __shfl_xor(a2v, d); a3  += __shfl_xor(a3, d);
            }
            if (tid == 0) {
                float aq = -2.f * alpha * a3;
                float bq = oma * a0v + alpha * (a1v - 4.f * a2v);
                float tv;
                if (aq > 0.f) tv = fminf(fmaxf(-bq / (2.f * aq + 1e-16f), 0.f), 1.f);
                else          tv = (aq + bq < 0.f) ? 1.f : 0.f;
                sBC[0] = tv;
            }
        }
        __syncthreads();
        const float tau = sBC[0];
        uint4 tw4 = Tb4[r]; unsigned tw1 = Tb1[r];
        uint4 cw4 = Cb4[r]; unsigned cw1 = Cb1[r];
        uint4 Dw4 = Db4[r]; unsigned Dw1 = Db1[r];
        float T[MN], C[MN], Dd[MN];
        T[0]=bflo(tw4.x); T[1]=bfhi(tw4.x); T[2]=bflo(tw4.y); T[3]=bfhi(tw4.y);
        T[4]=bflo(tw4.z); T[5]=bfhi(tw4.z); T[6]=bflo(tw4.w); T[7]=bfhi(tw4.w);
        T[8]=bflo(tw1);   T[9]=bfhi(tw1);
        C[0]=bflo(cw4.x); C[1]=bfhi(cw4.x); C[2]=bflo(cw4.y); C[3]=bfhi(cw4.y);
        C[4]=bflo(cw4.z); C[5]=bfhi(cw4.z); C[6]=bflo(cw4.w); C[7]=bfhi(cw4.w);
        C[8]=bflo(cw1);   C[9]=bfhi(cw1);
        Dd[0]=bflo(Dw4.x); Dd[1]=bfhi(Dw4.x); Dd[2]=bflo(Dw4.y); Dd[3]=bfhi(Dw4.y);
        Dd[4]=bflo(Dw4.z); Dd[5]=bfhi(Dw4.z); Dd[6]=bflo(Dw4.w); Dd[7]=bfhi(Dw4.w);
        Dd[8]=bflo(Dw1);   Dd[9]=bfhi(Dw1);
        float gw = 0.f, wass = 0.f;
        #pragma unroll
        for (int h = 0; h < 5; ++h) {
            float2 mv = *(const float2*)(Mb + (size_t)r * MN + 2*h);
            float Tf0 = T[2*h]   + tau * dd[2*h];
            float Tf1 = T[2*h+1] + tau * dd[2*h+1];
            float Cf0 = C[2*h]   + tau * Dd[2*h];
            float Cf1 = C[2*h+1] + tau * Dd[2*h+1];
            gw   += (cp + scq[2*h]   - 2.f * Cf0) * Tf0
                  + (cp + scq[2*h+1] - 2.f * Cf1) * Tf1;
            wass += mv.x * Tf0 + mv.y * Tf1;
        }
        #pragma unroll
        for (int d = 32; d; d >>= 1) {
            gw   += __shfl_xor(gw, d);
            wass += __shfl_xor(wass, d);
        }
        if ((tid & 63) == 0) { sRed[tid >> 6] = gw; sRed[NW + (tid >> 6)] = wass; }
        __syncthreads();
        ++st;
        if (tid == 0) {
            float sgw = 0.f, sws = 0.f;
            for (int w = 0; w < NW; ++w) { sgw += sRed[w]; sws += sRed[NW + w]; }
            slput(SLg + 4, st, __float_as_uint(sgw));
            slput(SLg + 5, st, __float_as_uint(sws));
        }
        if (g == 0) {
            if (tid < 16) {
                const int gg = tid & 7, which = tid >> 3;
                float val = __uint_as_float(slpoll(SLt + gg * 8 + 4 + which, st));
                val += __shfl_xor(val, 1);
                val += __shfl_xor(val, 2);
                val += __shfl_xor(val, 4);
                if (gg == 0) sRed[which] = val;
            }
            __syncthreads();
            if (tid == 0) out[t] = oma * sRed[1] + alpha * sRed[0];
        }
    }
}

extern "C" void kernel_launch(void* const* d_in, const int* in_sizes, int n_in,
                              void* d_out, int out_size, void* d_ws, size_t ws_size,
                              hipStream_t stream) {
    const float* x   = (const float*)d_in[0];
    const void*  ei  = d_in[1];
    const float* tpl = (const float*)d_in[2];
    const float* tfp = (const float*)d_in[3];
    const float* q0  = (const float*)d_in[4];
    const float* a0  = (const float*)d_in[5];
    float* outp = (float*)d_out;
    float* Wp   = (float*)d_ws;
    (void)hipFuncSetAttribute(reinterpret_cast<const void*>(&tfgw_kernel),
                              hipFuncAttributeMaxDynamicSharedMemorySize, LDS_DYN);
    void* args[] = { &x, &ei, &tpl, &tfp, &q0, &a0, &outp, &Wp };
    hipLaunchCooperativeKernel(reinterpret_cast<const void*>(&tfgw_kernel),
                               dim3(NBLK), dim3(TPB), args, LDS_DYN, stream);
}

// Round 13
// 1022.113 us; speedup vs baseline: 2.6542x; 2.6542x over previous
//
#include <hip/hip_runtime.h>
#include <hip/hip_cooperative_groups.h>

namespace cgx = cooperative_groups;

static constexpr int NN  = 6144;
static constexpr int NE  = 98304;
static constexpr int NF  = 128;
static constexpr int NT  = 16;
static constexpr int MN  = 10;
static constexpr int NCG = 5;
static constexpr int NSK = 50;
static constexpr int WPR = NN / 32;
static constexpr int TPB = 768;
static constexpr int NBLK = 256;
static constexpr int RPT = NN / TPB;   // 8 rows/thread
static constexpr int NW  = TPB / 64;   // 12 waves

static_assert(TPB * RPT == NN, "row mapping");

// workspace layout (float elements). T/C/D stored split: uint4 plane (cols 0-7)
// + u32 plane (cols 8-9). BM (setup-only) aliases T4..D4.
static constexpr size_t OFF_M   = 0;                               // fp32 [NT][NN][10]
static constexpr size_t OFF_T4  = OFF_M  + (size_t)NT * NN * MN;   // uint4 [NT][NN]
static constexpr size_t OFF_T1  = OFF_T4 + (size_t)NT * NN * 4;    // u32   [NT][NN]
static constexpr size_t OFF_C4  = OFF_T1 + (size_t)NT * NN;
static constexpr size_t OFF_C1  = OFF_C4 + (size_t)NT * NN * 4;
static constexpr size_t OFF_D4  = OFF_C1 + (size_t)NT * NN;
static constexpr size_t OFF_D1  = OFF_D4 + (size_t)NT * NN * 4;
static constexpr size_t OFF_RS  = OFF_D1 + (size_t)NT * NN;
static constexpr size_t OFF_DEG = OFF_RS + NN;
static constexpr size_t OFF_CI  = OFF_DEG + NN;                    // ushort[2*NE]
static constexpr size_t OFF_NNZ = OFF_CI + NE;

// LDS: dd planes as uint4 (cols 0-7) + u32 (cols 8-9); packed reduction buffer
static constexpr int LDS_PL  = NN * 20;          // 122880 B
static constexpr int LDS_SP  = TPB * 7 * 4;      // 21504 B (stride 7: conflict-free)
static constexpr int LDS_DYN = LDS_PL + LDS_SP;  // 144384 B -> 1 block/CU (3 waves/SIMD)

__device__ __forceinline__ unsigned f2bf(float f) {            // fp32 -> bf16 (rne)
    unsigned u = __float_as_uint(f);
    return (u + 0x7fffu + ((u >> 16) & 1u)) >> 16;
}
__device__ __forceinline__ unsigned packbf(float a, float b) { return f2bf(a) | (f2bf(b) << 16); }
__device__ __forceinline__ float bflo(unsigned w) { return __uint_as_float(w << 16); }
__device__ __forceinline__ float bfhi(unsigned w) { return __uint_as_float(w & 0xffff0000u); }

extern __shared__ char sMem[];

// amdgpu_waves_per_eu(3,3): LDS already caps us at 1 block/CU = 3 waves/SIMD,
// but the compiler can't see dynamic LDS and register-allocates for 6 waves
// (84 VGPR) + spills. Pinning occupancy unlocks the ~168-VGPR budget so the
// packed E rows (Ep[40]) stay in registers.
__global__ __launch_bounds__(TPB) __attribute__((amdgpu_waves_per_eu(3, 3)))
void tfgw_kernel(
    const float* __restrict__ x, const void* __restrict__ eiv,
    const float* __restrict__ tpl, const float* __restrict__ tf,
    const float* __restrict__ q0, const float* __restrict__ a0,
    float* __restrict__ out, float* __restrict__ W)
{
    __shared__ float sC2[MN * MN];
    __shared__ float sq[MN], scq[MN], sqC2[MN], sNSQ[MN];
    __shared__ unsigned svp[5];        // v packed bf16-pairs
    __shared__ float sRed[3 * NW];
    __shared__ float sBC[2];
    __shared__ float sDots[4];

    const int tid = threadIdx.x;
    const int bid = blockIdx.x;

    unsigned* BM    = (unsigned*)(W + OFF_T4);  // aliased; dead after setup
    int* rowst      = (int*)(W + OFF_RS);
    int* degi       = (int*)(W + OFF_DEG);
    unsigned short* colix = (unsigned short*)(W + OFF_CI);
    int* nnzc       = (int*)(W + OFF_NNZ);
    float* Mw  = W + OFF_M;

    uint4*    PL4x = (uint4*)sMem;                        // [NN]: dd cols 0-7
    unsigned* PL1x = (unsigned*)(sMem + NN * 16);         // [NN]: dd cols 8-9
    unsigned* sPp  = (unsigned*)(sMem + LDS_PL);          // [TPB*7] packed partials

    const float alpha  = 1.f / (1.f + __expf(-a0[0]));
    const float invn   = 1.f / (float)NN;
    const float alpha2 = 2.f * alpha;
    const float oma    = 1.f - alpha;

    cgx::grid_group grid = cgx::this_grid();

    // ---- P0: zero bitmap + nnz ----
    for (int idx = bid * TPB + tid; idx < NN * WPR; idx += NBLK * TPB) BM[idx] = 0u;
    if (bid == 0 && tid == 0) *nnzc = 0;
    grid.sync();

    // ---- P1: adjacency bits + feature cost M (sTF overlays sMem) ----
    {
        const unsigned* uw = (const unsigned*)eiv;
        const bool is64 = (uw[1] == 0u && uw[3] == 0u && uw[5] == 0u);
        for (int e = bid * TPB + tid; e < NE; e += NBLK * TPB) {
            int s, d;
            if (is64) {
                s = (int)((const long long*)eiv)[e];
                d = (int)((const long long*)eiv)[NE + e];
            } else {
                s = ((const int*)eiv)[e];
                d = ((const int*)eiv)[NE + e];
            }
            atomicOr(&BM[(size_t)s * WPR + (d >> 5)], 1u << (d & 31));
            atomicOr(&BM[(size_t)d * WPR + (s >> 5)], 1u << (s & 31));
        }
        float* sTF = (float*)sMem;
        const int t = bid >> 4, rb = bid & 15;
        for (int k = tid; k < MN * NF; k += TPB) sTF[k] = tf[t * MN * NF + k];
        __syncthreads();
        if (tid < MN) {
            float s = 0.f;
            for (int k = 0; k < NF; ++k) { float v = sTF[tid * NF + k]; s += v * v; }
            sNSQ[tid] = s;
        }
        __syncthreads();
        if (tid < 384) {
            const int i = rb * 384 + tid;
            const float4* x4 = (const float4*)(x + (size_t)i * NF);
            const float4* t4 = (const float4*)sTF;
            float acc[MN]; float xn = 0.f;
            #pragma unroll
            for (int j = 0; j < MN; ++j) acc[j] = 0.f;
            for (int k4 = 0; k4 < NF / 4; ++k4) {
                float4 xv = x4[k4];
                xn += xv.x * xv.x + xv.y * xv.y + xv.z * xv.z + xv.w * xv.w;
                #pragma unroll
                for (int j = 0; j < MN; ++j) {
                    float4 tv = t4[j * (NF / 4) + k4];
                    acc[j] += xv.x * tv.x + xv.y * tv.y + xv.z * tv.z + xv.w * tv.w;
                }
            }
            float* Mrow = Mw + (size_t)t * NN * MN + (size_t)i * MN;
            #pragma unroll
            for (int j = 0; j < MN; ++j) Mrow[j] = xn + sNSQ[j] - 2.f * acc[j];
        }
    }
    grid.sync();

    // ---- P2: degrees + CSR (ushort cols) ----
    {
        const int i = bid * TPB + tid;
        if (i < NN) {
            int cnt = 0;
            for (int w = 0; w < WPR; ++w) cnt += __popc(BM[(size_t)i * WPR + w]);
            int st = atomicAdd(nnzc, cnt);
            rowst[i] = st; degi[i] = cnt;
            int p = st;
            for (int w = 0; w < WPR; ++w) {
                unsigned m = BM[(size_t)i * WPR + w];
                while (m) { int b = __ffs(m) - 1; m &= m - 1; colix[p++] = (unsigned short)((w << 5) + b); }
            }
        }
    }
    grid.sync();     // last grid sync

    if (bid >= NT) return;

    // ================= block t owns template t =================
    const int t = bid;
    float* Mb = Mw + (size_t)t * NN * MN;
    uint4*    Tb4 = (uint4*)(W + OFF_T4) + (size_t)t * NN;
    unsigned* Tb1 = (unsigned*)(W + OFF_T1) + (size_t)t * NN;
    uint4*    Cb4 = (uint4*)(W + OFF_C4) + (size_t)t * NN;
    unsigned* Cb1 = (unsigned*)(W + OFF_C1) + (size_t)t * NN;
    uint4*    Db4 = (uint4*)(W + OFF_D4) + (size_t)t * NN;
    unsigned* Db1 = (unsigned*)(W + OFF_D1) + (size_t)t * NN;

    if (tid == 0) {
        float qv[MN]; float qm = -1e30f;
        for (int j = 0; j < MN; ++j) { qv[j] = q0[t * MN + j]; qm = fmaxf(qm, qv[j]); }
        float qs = 0.f;
        for (int j = 0; j < MN; ++j) { qv[j] = __expf(qv[j] - qm); qs += qv[j]; }
        for (int j = 0; j < MN; ++j) { qv[j] /= qs; sq[j] = qv[j]; }
        for (int j = 0; j < MN; ++j) {
            float s2 = 0.f, s1 = 0.f;
            for (int k = 0; k < MN; ++k) {
                float cjk = tpl[t * MN * MN + j * MN + k];
                s2 += cjk * cjk * qv[k];
                s1 += tpl[t * MN * MN + k * MN + j] * qv[k];
            }
            scq[j] = s2; sqC2[j] = s1;
        }
    }
    for (int k = tid; k < MN * MN; k += TPB) sC2[k] = tpl[t * MN * MN + k];
    __syncthreads();

    unsigned Ep[RPT * 5];   // packed bf16 E rows — REGISTERS (the whole point)

    for (int cgi = 0; cgi < NCG; ++cgi) {
        // ---- tau from previous dots; tau==0 (cgi>0) => fixed point ----
        if (tid == 0) {
            float tau = 0.f;
            if (cgi > 0) {
                float a = -2.f * alpha * sDots[3];
                float b = oma * sDots[0] + alpha * (sDots[1] - 4.f * sDots[2]);
                if (a > 0.f) tau = fminf(fmaxf(-b / (2.f * a + 1e-16f), 0.f), 1.f);
                else         tau = (a + b < 0.f) ? 1.f : 0.f;
            }
            sBC[0] = tau;
        }
        __syncthreads();
        const float tau = sBC[0];
        if (cgi > 0 && tau == 0.f) break;

        // ---- Phase A: update T,C (bf16 globals; dd from planes); g -> Ep regs ----
        float gmax = 0.f;
        #pragma unroll
        for (int k = 0; k < RPT; ++k) {
            const int r = tid + k * TPB;
            const float cp = (float)degi[r] * invn;
            float C[MN];
            if (cgi == 0) {
                uint4 tw4; unsigned tw1; uint4 cw4; unsigned cw1;
                tw4.x = packbf(sq[0]*invn, sq[1]*invn); tw4.y = packbf(sq[2]*invn, sq[3]*invn);
                tw4.z = packbf(sq[4]*invn, sq[5]*invn); tw4.w = packbf(sq[6]*invn, sq[7]*invn);
                tw1   = packbf(sq[8]*invn, sq[9]*invn);
                cw4.x = packbf(cp*sqC2[0], cp*sqC2[1]); cw4.y = packbf(cp*sqC2[2], cp*sqC2[3]);
                cw4.z = packbf(cp*sqC2[4], cp*sqC2[5]); cw4.w = packbf(cp*sqC2[6], cp*sqC2[7]);
                cw1   = packbf(cp*sqC2[8], cp*sqC2[9]);
                Tb4[r] = tw4; Tb1[r] = tw1; Cb4[r] = cw4; Cb1[r] = cw1;
                C[0]=bflo(cw4.x); C[1]=bfhi(cw4.x); C[2]=bflo(cw4.y); C[3]=bfhi(cw4.y);
                C[4]=bflo(cw4.z); C[5]=bfhi(cw4.z); C[6]=bflo(cw4.w); C[7]=bfhi(cw4.w);
                C[8]=bflo(cw1);   C[9]=bfhi(cw1);
            } else {
                float dd[MN];
                uint4 a = PL4x[r]; unsigned b4 = PL1x[r];
                dd[0]=bflo(a.x); dd[1]=bfhi(a.x); dd[2]=bflo(a.y); dd[3]=bfhi(a.y);
                dd[4]=bflo(a.z); dd[5]=bfhi(a.z); dd[6]=bflo(a.w); dd[7]=bfhi(a.w);
                dd[8]=bflo(b4);  dd[9]=bfhi(b4);
                uint4 tw4 = Tb4[r]; unsigned tw1 = Tb1[r];
                uint4 cw4 = Cb4[r]; unsigned cw1 = Cb1[r];
                uint4 Dw4 = Db4[r]; unsigned Dw1 = Db1[r];
                float T[MN], Dd[MN];
                T[0]=bflo(tw4.x); T[1]=bfhi(tw4.x); T[2]=bflo(tw4.y); T[3]=bfhi(tw4.y);
                T[4]=bflo(tw4.z); T[5]=bfhi(tw4.z); T[6]=bflo(tw4.w); T[7]=bfhi(tw4.w);
                T[8]=bflo(tw1);   T[9]=bfhi(tw1);
                C[0]=bflo(cw4.x); C[1]=bfhi(cw4.x); C[2]=bflo(cw4.y); C[3]=bfhi(cw4.y);
                C[4]=bflo(cw4.z); C[5]=bfhi(cw4.z); C[6]=bflo(cw4.w); C[7]=bfhi(cw4.w);
                C[8]=bflo(cw1);   C[9]=bfhi(cw1);
                Dd[0]=bflo(Dw4.x); Dd[1]=bfhi(Dw4.x); Dd[2]=bflo(Dw4.y); Dd[3]=bfhi(Dw4.y);
                Dd[4]=bflo(Dw4.z); Dd[5]=bfhi(Dw4.z); Dd[6]=bflo(Dw4.w); Dd[7]=bfhi(Dw4.w);
                Dd[8]=bflo(Dw1);   Dd[9]=bfhi(Dw1);
                #pragma unroll
                for (int j = 0; j < MN; ++j) { T[j] += tau * dd[j]; C[j] += tau * Dd[j]; }
                uint4 n4; unsigned n1;
                n4.x = packbf(T[0],T[1]); n4.y = packbf(T[2],T[3]);
                n4.z = packbf(T[4],T[5]); n4.w = packbf(T[6],T[7]); n1 = packbf(T[8],T[9]);
                Tb4[r] = n4; Tb1[r] = n1;
                n4.x = packbf(C[0],C[1]); n4.y = packbf(C[2],C[3]);
                n4.z = packbf(C[4],C[5]); n4.w = packbf(C[6],C[7]); n1 = packbf(C[8],C[9]);
                Cb4[r] = n4; Cb1[r] = n1;
                C[0]=bflo(n4.x); C[1]=bfhi(n4.x); C[2]=bflo(n4.y); C[3]=bfhi(n4.y);
                C[4]=bflo(n4.z); C[5]=bfhi(n4.z); C[6]=bflo(n4.w); C[7]=bfhi(n4.w);
                C[8]=bflo(n1);   C[9]=bfhi(n1);
            }
            float g[MN];
            #pragma unroll
            for (int h = 0; h < 5; ++h) {
                float2 mv = *(const float2*)(Mb + (size_t)r * MN + 2*h);
                g[2*h]   = oma * mv.x + alpha2 * (cp + scq[2*h]   - 2.f * C[2*h]);
                g[2*h+1] = oma * mv.y + alpha2 * (cp + scq[2*h+1] - 2.f * C[2*h+1]);
                gmax = fmaxf(gmax, fmaxf(__builtin_fabsf(g[2*h]), __builtin_fabsf(g[2*h+1])));
            }
            #pragma unroll
            for (int h = 0; h < 5; ++h) Ep[k*5 + h] = packbf(g[2*h], g[2*h+1]);
        }
        #pragma unroll
        for (int d = 32; d; d >>= 1) gmax = fmaxf(gmax, __shfl_xor(gmax, d));
        if ((tid & 63) == 0) sRed[tid >> 6] = gmax;
        __syncthreads();
        if (tid == 0) {
            float m = sRed[0];
            for (int w = 1; w < NW; ++w) m = fmaxf(m, sRed[w]);
            sBC[1] = 1.f / (0.05f * m + 1e-8f);
        }
        __syncthreads();
        const float invreg = sBC[1];

        // ---- Phase B: E = exp(-g*invreg), in registers ----
        #pragma unroll
        for (int k = 0; k < RPT; ++k)
            #pragma unroll
            for (int h = 0; h < 5; ++h) {
                unsigned w = Ep[k*5 + h];
                Ep[k*5 + h] = packbf(__expf(-bflo(w) * invreg), __expf(-bfhi(w) * invreg));
            }

        // ---- Sinkhorn iter 0 (u = 1) — only for cgi==0; else warm-start ----
        if (cgi == 0) {
            float a[MN];
            #pragma unroll
            for (int j = 0; j < MN; ++j) a[j] = 0.f;
            #pragma unroll
            for (int k = 0; k < RPT; ++k)
                #pragma unroll
                for (int h = 0; h < 5; ++h) {
                    unsigned w = Ep[k*5 + h];
                    a[2*h] += bflo(w); a[2*h+1] += bfhi(w);
                }
            #pragma unroll
            for (int p = 0; p < 5; ++p) sPp[tid * 7 + p] = packbf(a[2*p], a[2*p+1]);
            __syncthreads();
            if (tid < 320) {
                const int p = tid >> 6, c = tid & 63;
                float s0 = 0.f, s1 = 0.f;
                #pragma unroll
                for (int kk = 0; kk < NW; ++kk) {
                    unsigned w = sPp[(c + (kk << 6)) * 7 + p];
                    s0 += bflo(w); s1 += bfhi(w);
                }
                #pragma unroll
                for (int d = 32; d; d >>= 1) { s0 += __shfl_xor(s0, d); s1 += __shfl_xor(s1, d); }
                if (c == 0) svp[p] = packbf(sq[2*p] / s0, sq[2*p+1] / s1);
            }
            __syncthreads();
        }

        // ---- Sinkhorn fused (u,v) x50 (rows in registers; no DS row traffic) ----
        for (int it = 1; it <= NSK; ++it) {
            float vv[MN];
            #pragma unroll
            for (int p = 0; p < 5; ++p) {
                unsigned w = svp[p];
                vv[2*p] = bflo(w); vv[2*p+1] = bfhi(w);
            }
            float a[MN];
            #pragma unroll
            for (int j = 0; j < MN; ++j) a[j] = 0.f;
            #pragma unroll
            for (int k = 0; k < RPT; ++k) {
                float e[MN];
                #pragma unroll
                for (int h = 0; h < 5; ++h) {
                    unsigned w = Ep[k*5 + h];
                    e[2*h] = bflo(w); e[2*h+1] = bfhi(w);
                }
                float R = 0.f;
                #pragma unroll
                for (int j = 0; j < MN; ++j) R += e[j] * vv[j];
                const float u = invn * __builtin_amdgcn_rcpf(R);
                #pragma unroll
                for (int j = 0; j < MN; ++j) a[j] += e[j] * u;
            }
            #pragma unroll
            for (int p = 0; p < 5; ++p) sPp[tid * 7 + p] = packbf(a[2*p], a[2*p+1]);
            __syncthreads();
            if (tid < 320) {
                const int p = tid >> 6, c = tid & 63;
                float s0 = 0.f, s1 = 0.f;
                #pragma unroll
                for (int kk = 0; kk < NW; ++kk) {
                    unsigned w = sPp[(c + (kk << 6)) * 7 + p];
                    s0 += bflo(w); s1 += bfhi(w);
                }
                #pragma unroll
                for (int d = 32; d; d >>= 1) { s0 += __shfl_xor(s0, d); s1 += __shfl_xor(s1, d); }
                if (c == 0) svp[p] = packbf(sq[2*p] / s0, sq[2*p+1] / s1);
            }
            __syncthreads();
        }

        // ---- dT phase: u from final v; dd = u e v - T; dots; dd -> planes ----
        {
            float vv[MN];
            #pragma unroll
            for (int p = 0; p < 5; ++p) {
                unsigned w = svp[p];
                vv[2*p] = bflo(w); vv[2*p+1] = bfhi(w);
            }
            float sMdT = 0.f, sCdT = 0.f, sCTdT = 0.f;
            #pragma unroll
            for (int k = 0; k < RPT; ++k) {
                const int r = tid + k * TPB;
                const float cp = (float)degi[r] * invn;
                float e[MN], dd[MN];
                #pragma unroll
                for (int h = 0; h < 5; ++h) {
                    unsigned w = Ep[k*5 + h];
                    e[2*h] = bflo(w); e[2*h+1] = bfhi(w);
                }
                float R = 0.f;
                #pragma unroll
                for (int j = 0; j < MN; ++j) R += e[j] * vv[j];
                const float u = invn * __builtin_amdgcn_rcpf(R);
                uint4 tw4 = Tb4[r]; unsigned tw1 = Tb1[r];
                uint4 cw4 = Cb4[r]; unsigned cw1 = Cb1[r];
                float T[MN], C[MN];
                T[0]=bflo(tw4.x); T[1]=bfhi(tw4.x); T[2]=bflo(tw4.y); T[3]=bfhi(tw4.y);
                T[4]=bflo(tw4.z); T[5]=bfhi(tw4.z); T[6]=bflo(tw4.w); T[7]=bfhi(tw4.w);
                T[8]=bflo(tw1);   T[9]=bfhi(tw1);
                C[0]=bflo(cw4.x); C[1]=bfhi(cw4.x); C[2]=bflo(cw4.y); C[3]=bfhi(cw4.y);
                C[4]=bflo(cw4.z); C[5]=bfhi(cw4.z); C[6]=bflo(cw4.w); C[7]=bfhi(cw4.w);
                C[8]=bflo(cw1);   C[9]=bfhi(cw1);
                #pragma unroll
                for (int h = 0; h < 5; ++h) {
                    float2 mv = *(const float2*)(Mb + (size_t)r * MN + 2*h);
                    float d0 = u * e[2*h]   * vv[2*h]   - T[2*h];
                    float d1 = u * e[2*h+1] * vv[2*h+1] - T[2*h+1];
                    dd[2*h] = d0; dd[2*h+1] = d1;
                    sMdT  += mv.x * d0 + mv.y * d1;
                    sCdT  += (cp + scq[2*h]) * d0 + (cp + scq[2*h+1]) * d1;
                    sCTdT += C[2*h] * d0 + C[2*h+1] * d1;
                }
                PL4x[r] = make_uint4(packbf(dd[0],dd[1]), packbf(dd[2],dd[3]),
                                     packbf(dd[4],dd[5]), packbf(dd[6],dd[7]));
                PL1x[r] = packbf(dd[8], dd[9]);
            }
            #pragma unroll
            for (int d = 32; d; d >>= 1) {
                sMdT  += __shfl_xor(sMdT, d);
                sCdT  += __shfl_xor(sCdT, d);
                sCTdT += __shfl_xor(sCTdT, d);
            }
            if ((tid & 63) == 0) {
                const int w = tid >> 6;
                sRed[w] = sMdT; sRed[NW + w] = sCdT; sRed[2*NW + w] = sCTdT;
            }
            __syncthreads();   // dots staged AND dd planes visible block-wide
            if (tid == 0) {
                float r0 = 0.f, r1 = 0.f, r2 = 0.f;
                for (int w = 0; w < NW; ++w) { r0 += sRed[w]; r1 += sRed[NW+w]; r2 += sRed[2*NW+w]; }
                sDots[0] = r0; sDots[1] = r1; sDots[2] = r2;
            }
        }

        // ---- SpMM: D = C1 dT C2 (gather dd planes), sA = <D,dd>; D -> globals ----
        {
            float dot = 0.f;
            #pragma unroll
            for (int k = 0; k < RPT; ++k) {
                const int r = tid + k * TPB;
                float y[MN];
                #pragma unroll
                for (int j = 0; j < MN; ++j) y[j] = 0.f;
                const int st = rowst[r], dg = degi[r];
                const unsigned short* cl = colix + st;
                for (int e = 0; e < dg; ++e) {
                    const int j = cl[e];
                    uint4 q = PL4x[j]; unsigned b4 = PL1x[j];
                    y[0] += bflo(q.x); y[1] += bfhi(q.x);
                    y[2] += bflo(q.y); y[3] += bfhi(q.y);
                    y[4] += bflo(q.z); y[5] += bfhi(q.z);
                    y[6] += bflo(q.w); y[7] += bfhi(q.w);
                    y[8] += bflo(b4);  y[9] += bfhi(b4);
                }
                uint4 q = PL4x[r]; unsigned b4 = PL1x[r];
                float dd[MN];
                dd[0]=bflo(q.x); dd[1]=bfhi(q.x); dd[2]=bflo(q.y); dd[3]=bfhi(q.y);
                dd[4]=bflo(q.z); dd[5]=bfhi(q.z); dd[6]=bflo(q.w); dd[7]=bfhi(q.w);
                dd[8]=bflo(b4);  dd[9]=bfhi(b4);
                float o[MN];
                #pragma unroll
                for (int h = 0; h < 5; ++h) {
                    float o0 = 0.f, o1 = 0.f;
                    #pragma unroll
                    for (int j = 0; j < MN; ++j) {
                        o0 += y[j] * sC2[j * MN + 2*h];
                        o1 += y[j] * sC2[j * MN + 2*h + 1];
                    }
                    o[2*h] = o0; o[2*h+1] = o1;
                    dot += o0 * dd[2*h] + o1 * dd[2*h+1];
                }
                Db4[r] = make_uint4(packbf(o[0],o[1]), packbf(o[2],o[3]),
                                    packbf(o[4],o[5]), packbf(o[6],o[7]));
                Db1[r] = packbf(o[8], o[9]);
            }
            #pragma unroll
            for (int d = 32; d; d >>= 1) dot += __shfl_xor(dot, d);
            if ((tid & 63) == 0) sRed[tid >> 6] = dot;
            __syncthreads();
            if (tid == 0) {
                float s = 0.f;
                for (int w = 0; w < NW; ++w) s += sRed[w];
                sDots[3] = s;
            }
            __syncthreads();
        }
    }

    // ---- F: final tau + objective (T,C,D from bf16 globals; dd from planes) ----
    if (tid == 0) {
        float a = -2.f * alpha * sDots[3];
        float b = oma * sDots[0] + alpha * (sDots[1] - 4.f * sDots[2]);
        float tau;
        if (a > 0.f) tau = fminf(fmaxf(-b / (2.f * a + 1e-16f), 0.f), 1.f);
        else         tau = (a + b < 0.f) ? 1.f : 0.f;
        sBC[0] = tau;
    }
    __syncthreads();
    {
        const float tau = sBC[0];
        float gw = 0.f, wass = 0.f;
        #pragma unroll
        for (int k = 0; k < RPT; ++k) {
            const int r = tid + k * TPB;
            const float cp = (float)degi[r] * invn;
            uint4 q = PL4x[r]; unsigned b4 = PL1x[r];
            float dd[MN];
            dd[0]=bflo(q.x); dd[1]=bfhi(q.x); dd[2]=bflo(q.y); dd[3]=bfhi(q.y);
            dd[4]=bflo(q.z); dd[5]=bfhi(q.z); dd[6]=bflo(q.w); dd[7]=bfhi(q.w);
            dd[8]=bflo(b4);  dd[9]=bfhi(b4);
            uint4 tw4 = Tb4[r]; unsigned tw1 = Tb1[r];
            uint4 cw4 = Cb4[r]; unsigned cw1 = Cb1[r];
            uint4 Dw4 = Db4[r]; unsigned Dw1 = Db1[r];
            float T[MN], C[MN], Dd[MN];
            T[0]=bflo(tw4.x); T[1]=bfhi(tw4.x); T[2]=bflo(tw4.y); T[3]=bfhi(tw4.y);
            T[4]=bflo(tw4.z); T[5]=bfhi(tw4.z); T[6]=bflo(tw4.w); T[7]=bfhi(tw4.w);
            T[8]=bflo(tw1);   T[9]=bfhi(tw1);
            C[0]=bflo(cw4.x); C[1]=bfhi(cw4.x); C[2]=bflo(cw4.y); C[3]=bfhi(cw4.y);
            C[4]=bflo(cw4.z); C[5]=bfhi(cw4.z); C[6]=bflo(cw4.w); C[7]=bfhi(cw4.w);
            C[8]=bflo(cw1);   C[9]=bfhi(cw1);
            Dd[0]=bflo(Dw4.x); Dd[1]=bfhi(Dw4.x); Dd[2]=bflo(Dw4.y); Dd[3]=bfhi(Dw4.y);
            Dd[4]=bflo(Dw4.z); Dd[5]=bfhi(Dw4.z); Dd[6]=bflo(Dw4.w); Dd[7]=bfhi(Dw4.w);
            Dd[8]=bflo(Dw1);   Dd[9]=bfhi(Dw1);
            #pragma unroll
            for (int h = 0; h < 5; ++h) {
                float2 mv = *(const float2*)(Mb + (size_t)r * MN + 2*h);
                float Tf0 = T[2*h]   + tau * dd[2*h];
                float Tf1 = T[2*h+1] + tau * dd[2*h+1];
                float Cf0 = C[2*h]   + tau * Dd[2*h];
                float Cf1 = C[2*h+1] + tau * Dd[2*h+1];
                gw   += (cp + scq[2*h]   - 2.f * Cf0) * Tf0
                      + (cp + scq[2*h+1] - 2.f * Cf1) * Tf1;
                wass += mv.x * Tf0 + mv.y * Tf1;
            }
        }
        #pragma unroll
        for (int d = 32; d; d >>= 1) {
            gw   += __shfl_xor(gw, d);
            wass += __shfl_xor(wass, d);
        }
        if ((tid & 63) == 0) { sRed[tid >> 6] = gw; sRed[NW + (tid >> 6)] = wass; }
        __syncthreads();
        if (tid == 0) {
            float g = 0.f, ws = 0.f;
            for (int w = 0; w < NW; ++w) { g += sRed[w]; ws += sRed[NW + w]; }
            out[t] = oma * ws + alpha * g;
        }
    }
}

extern "C" void kernel_launch(void* const* d_in, const int* in_sizes, int n_in,
                              void* d_out, int out_size, void* d_ws, size_t ws_size,
                              hipStream_t stream) {
    const float* x   = (const float*)d_in[0];
    const void*  ei  = d_in[1];
    const float* tpl = (const float*)d_in[2];
    const float* tfp = (const float*)d_in[3];
    const float* q0  = (const float*)d_in[4];
    const float* a0  = (const float*)d_in[5];
    float* outp = (float*)d_out;
    float* Wp   = (float*)d_ws;
    (void)hipFuncSetAttribute(reinterpret_cast<const void*>(&tfgw_kernel),
                              hipFuncAttributeMaxDynamicSharedMemorySize, LDS_DYN);
    void* args[] = { &x, &ei, &tpl, &tfp, &q0, &a0, &outp, &Wp };
    hipLaunchCooperativeKernel(reinterpret_cast<const void*>(&tfgw_kernel),
                               dim3(NBLK), dim3(TPB), args, LDS_DYN, stream);
}

// Round 14
// 720.048 us; speedup vs baseline: 3.7676x; 1.4195x over previous
//
#include <hip/hip_runtime.h>
#include <hip/hip_cooperative_groups.h>

namespace cgx = cooperative_groups;

static constexpr int NN  = 6144;
static constexpr int NE  = 98304;
static constexpr int NF  = 128;
static constexpr int NT  = 16;
static constexpr int MN  = 10;
static constexpr int NCG = 5;
static constexpr int NSK = 50;
static constexpr int WPR = NN / 32;
static constexpr int TPB = 768;
static constexpr int NBLK = 256;
static constexpr int RPT = NN / TPB;   // 8 rows/thread
static constexpr int NW  = TPB / 64;   // 12 waves

static_assert(TPB * RPT == NN, "row mapping");

// workspace layout (float elements); BM (setup-only) aliases T+C+D region
static constexpr size_t OFF_M   = 0;                              // fp32 [NT][NN][10]
static constexpr size_t OFF_T   = OFF_M  + (size_t)NT * NN * MN;  // u32 bf16-pairs [NT][NN][5]
static constexpr size_t OFF_C   = OFF_T  + (size_t)NT * NN * 5;
static constexpr size_t OFF_D   = OFF_C  + (size_t)NT * NN * 5;
static constexpr size_t OFF_RS  = OFF_D  + (size_t)NT * NN * 5;
static constexpr size_t OFF_DEG = OFF_RS + NN;
static constexpr size_t OFF_CI  = OFF_DEG + NN;                   // ushort[2*NE] in NE floats
static constexpr size_t OFF_NNZ = OFF_CI + NE;

// LDS: rows as uint4 (cols 0-7) + u32 (cols 8-9); packed reduction buffer
static constexpr int LDS_PL  = NN * 20;          // 122880 B
static constexpr int LDS_SP  = TPB * 7 * 4;      // 21504 B (stride 7: conflict-free)
static constexpr int LDS_DYN = LDS_PL + LDS_SP;  // 144384 B

__device__ __forceinline__ unsigned f2bf(float f) {            // fp32 -> bf16 (rne)
    unsigned u = __float_as_uint(f);
    return (u + 0x7fffu + ((u >> 16) & 1u)) >> 16;
}
__device__ __forceinline__ unsigned packbf(float a, float b) { return f2bf(a) | (f2bf(b) << 16); }
__device__ __forceinline__ float bflo(unsigned w) { return __uint_as_float(w << 16); }
__device__ __forceinline__ float bfhi(unsigned w) { return __uint_as_float(w & 0xffff0000u); }

extern __shared__ char sMem[];

__global__ __launch_bounds__(TPB) void tfgw_kernel(
    const float* __restrict__ x, const void* __restrict__ eiv,
    const float* __restrict__ tpl, const float* __restrict__ tf,
    const float* __restrict__ q0, const float* __restrict__ a0,
    float* __restrict__ out, float* __restrict__ W)
{
    __shared__ float sC2[MN * MN];
    __shared__ float sq[MN], scq[MN], sqC2[MN], sNSQ[MN];
    __shared__ unsigned svp[5];        // v packed bf16-pairs (row threads read this)
    __shared__ float sVf[MN];          // v fp32 (reducer lanes only: convergence test)
    __shared__ float sCv[5];
    __shared__ float sRed[3 * NW];
    __shared__ float sBC[2];
    __shared__ float sDots[4];

    const int tid = threadIdx.x;
    const int bid = blockIdx.x;

    unsigned* BM    = (unsigned*)(W + OFF_T);   // aliased; dead after setup
    int* rowst      = (int*)(W + OFF_RS);
    int* degi       = (int*)(W + OFF_DEG);
    unsigned short* colix = (unsigned short*)(W + OFF_CI);
    int* nnzc       = (int*)(W + OFF_NNZ);
    float* Mw  = W + OFF_M;
    unsigned* Tg = (unsigned*)(W + OFF_T);
    unsigned* Cg = (unsigned*)(W + OFF_C);
    unsigned* Dg = (unsigned*)(W + OFF_D);

    uint4*    PL4x = (uint4*)sMem;                        // [NN]: cols 0-7
    unsigned* PL1x = (unsigned*)(sMem + NN * 16);         // [NN]: cols 8-9
    unsigned* sPp  = (unsigned*)(sMem + LDS_PL);          // [TPB*7] packed partials

    const float alpha  = 1.f / (1.f + __expf(-a0[0]));
    const float invn   = 1.f / (float)NN;
    const float alpha2 = 2.f * alpha;
    const float oma    = 1.f - alpha;

    cgx::grid_group grid = cgx::this_grid();

    // ---- P0: zero bitmap + nnz ----
    for (int idx = bid * TPB + tid; idx < NN * WPR; idx += NBLK * TPB) BM[idx] = 0u;
    if (bid == 0 && tid == 0) *nnzc = 0;
    grid.sync();

    // ---- P1: adjacency bits + feature cost M (sTF overlays sMem) ----
    {
        const unsigned* uw = (const unsigned*)eiv;
        const bool is64 = (uw[1] == 0u && uw[3] == 0u && uw[5] == 0u);
        for (int e = bid * TPB + tid; e < NE; e += NBLK * TPB) {
            int s, d;
            if (is64) {
                s = (int)((const long long*)eiv)[e];
                d = (int)((const long long*)eiv)[NE + e];
            } else {
                s = ((const int*)eiv)[e];
                d = ((const int*)eiv)[NE + e];
            }
            atomicOr(&BM[(size_t)s * WPR + (d >> 5)], 1u << (d & 31));
            atomicOr(&BM[(size_t)d * WPR + (s >> 5)], 1u << (s & 31));
        }
        float* sTF = (float*)sMem;
        const int t = bid >> 4, rb = bid & 15;
        for (int k = tid; k < MN * NF; k += TPB) sTF[k] = tf[t * MN * NF + k];
        __syncthreads();
        if (tid < MN) {
            float s = 0.f;
            for (int k = 0; k < NF; ++k) { float v = sTF[tid * NF + k]; s += v * v; }
            sNSQ[tid] = s;
        }
        __syncthreads();
        if (tid < 384) {
            const int i = rb * 384 + tid;
            const float4* x4 = (const float4*)(x + (size_t)i * NF);
            const float4* t4 = (const float4*)sTF;
            float acc[MN]; float xn = 0.f;
            #pragma unroll
            for (int j = 0; j < MN; ++j) acc[j] = 0.f;
            for (int k4 = 0; k4 < NF / 4; ++k4) {
                float4 xv = x4[k4];
                xn += xv.x * xv.x + xv.y * xv.y + xv.z * xv.z + xv.w * xv.w;
                #pragma unroll
                for (int j = 0; j < MN; ++j) {
                    float4 tv = t4[j * (NF / 4) + k4];
                    acc[j] += xv.x * tv.x + xv.y * tv.y + xv.z * tv.z + xv.w * tv.w;
                }
            }
            float* Mrow = Mw + (size_t)t * NN * MN + (size_t)i * MN;
            #pragma unroll
            for (int j = 0; j < MN; ++j) Mrow[j] = xn + sNSQ[j] - 2.f * acc[j];
        }
    }
    grid.sync();

    // ---- P2: degrees + CSR (ushort cols) ----
    {
        const int i = bid * TPB + tid;
        if (i < NN) {
            int cnt = 0;
            for (int w = 0; w < WPR; ++w) cnt += __popc(BM[(size_t)i * WPR + w]);
            int st = atomicAdd(nnzc, cnt);
            rowst[i] = st; degi[i] = cnt;
            int p = st;
            for (int w = 0; w < WPR; ++w) {
                unsigned m = BM[(size_t)i * WPR + w];
                while (m) { int b = __ffs(m) - 1; m &= m - 1; colix[p++] = (unsigned short)((w << 5) + b); }
            }
        }
    }
    grid.sync();     // last grid sync

    if (bid >= NT) return;

    // ================= block t owns template t =================
    const int t = bid;
    float* Mb = Mw + (size_t)t * NN * MN;
    unsigned* Tb = Tg + (size_t)t * NN * 5;
    unsigned* Cb = Cg + (size_t)t * NN * 5;
    unsigned* Db = Dg + (size_t)t * NN * 5;

    if (tid == 0) {
        float qv[MN]; float qm = -1e30f;
        for (int j = 0; j < MN; ++j) { qv[j] = q0[t * MN + j]; qm = fmaxf(qm, qv[j]); }
        float qs = 0.f;
        for (int j = 0; j < MN; ++j) { qv[j] = __expf(qv[j] - qm); qs += qv[j]; }
        for (int j = 0; j < MN; ++j) { qv[j] /= qs; sq[j] = qv[j]; }
        for (int j = 0; j < MN; ++j) {
            float s2 = 0.f, s1 = 0.f;
            for (int k = 0; k < MN; ++k) {
                float cjk = tpl[t * MN * MN + j * MN + k];
                s2 += cjk * cjk * qv[k];
                s1 += tpl[t * MN * MN + k * MN + j] * qv[k];
            }
            scq[j] = s2; sqC2[j] = s1;
        }
    }
    for (int k = tid; k < MN * MN; k += TPB) sC2[k] = tpl[t * MN * MN + k];
    __syncthreads();

    float uu[RPT];

    for (int cgi = 0; cgi < NCG; ++cgi) {
        // ---- tau from previous dots; tau==0 (cgi>0) => fixed point ----
        if (tid == 0) {
            float tau = 0.f;
            if (cgi > 0) {
                float a = -2.f * alpha * sDots[3];
                float b = oma * sDots[0] + alpha * (sDots[1] - 4.f * sDots[2]);
                if (a > 0.f) tau = fminf(fmaxf(-b / (2.f * a + 1e-16f), 0.f), 1.f);
                else         tau = (a + b < 0.f) ? 1.f : 0.f;
            }
            sBC[0] = tau;
        }
        __syncthreads();
        const float tau = sBC[0];
        if (cgi > 0 && tau == 0.f) break;

        // ---- Phase A: update T,C (bf16 globals; dd from planes); g -> planes ----
        float gmax = 0.f;
        #pragma unroll
        for (int k = 0; k < RPT; ++k) {
            const int r = tid + k * TPB;
            const float cp = (float)degi[r] * invn;
            const size_t b5 = (size_t)r * 5;
            float C[MN];
            if (cgi == 0) {
                #pragma unroll
                for (int h = 0; h < 5; ++h) {
                    unsigned tw = packbf(sq[2*h] * invn, sq[2*h+1] * invn);
                    unsigned cw = packbf(cp * sqC2[2*h], cp * sqC2[2*h+1]);
                    Tb[b5 + h] = tw; Cb[b5 + h] = cw;
                    C[2*h] = bflo(cw); C[2*h+1] = bfhi(cw);
                }
            } else {
                float dd[MN];
                uint4 a = PL4x[r]; unsigned b4 = PL1x[r];
                dd[0]=bflo(a.x); dd[1]=bfhi(a.x); dd[2]=bflo(a.y); dd[3]=bfhi(a.y);
                dd[4]=bflo(a.z); dd[5]=bfhi(a.z); dd[6]=bflo(a.w); dd[7]=bfhi(a.w);
                dd[8]=bflo(b4);  dd[9]=bfhi(b4);
                #pragma unroll
                for (int h = 0; h < 5; ++h) {
                    unsigned tw = Tb[b5 + h], cw = Cb[b5 + h], Dw = Db[b5 + h];
                    float T0 = bflo(tw) + tau * dd[2*h];
                    float T1 = bfhi(tw) + tau * dd[2*h+1];
                    float C0 = bflo(cw) + tau * bflo(Dw);
                    float C1v = bfhi(cw) + tau * bfhi(Dw);
                    unsigned ntw = packbf(T0, T1), ncw = packbf(C0, C1v);
                    Tb[b5 + h] = ntw; Cb[b5 + h] = ncw;
                    C[2*h] = bflo(ncw); C[2*h+1] = bfhi(ncw);
                }
            }
            float g[MN];
            #pragma unroll
            for (int h = 0; h < 5; ++h) {
                float2 mv = *(const float2*)(Mb + (size_t)r * MN + 2*h);
                g[2*h]   = oma * mv.x + alpha2 * (cp + scq[2*h]   - 2.f * C[2*h]);
                g[2*h+1] = oma * mv.y + alpha2 * (cp + scq[2*h+1] - 2.f * C[2*h+1]);
                gmax = fmaxf(gmax, fmaxf(__builtin_fabsf(g[2*h]), __builtin_fabsf(g[2*h+1])));
            }
            PL4x[r] = make_uint4(packbf(g[0],g[1]), packbf(g[2],g[3]),
                                 packbf(g[4],g[5]), packbf(g[6],g[7]));
            PL1x[r] = packbf(g[8], g[9]);
        }
        #pragma unroll
        for (int d = 32; d; d >>= 1) gmax = fmaxf(gmax, __shfl_xor(gmax, d));
        if ((tid & 63) == 0) sRed[tid >> 6] = gmax;
        __syncthreads();
        if (tid == 0) {
            float m = sRed[0];
            for (int w = 1; w < NW; ++w) m = fmaxf(m, sRed[w]);
            sBC[1] = 1.f / (0.05f * m + 1e-8f);
        }
        __syncthreads();
        const float invreg = sBC[1];

        // ---- Phase B: E = exp(-g*invreg), in place (own rows only; no barrier) ----
        #pragma unroll
        for (int k = 0; k < RPT; ++k) {
            const int r = tid + k * TPB;
            uint4 a = PL4x[r]; unsigned b4 = PL1x[r];
            float g[MN];
            g[0]=bflo(a.x); g[1]=bfhi(a.x); g[2]=bflo(a.y); g[3]=bfhi(a.y);
            g[4]=bflo(a.z); g[5]=bfhi(a.z); g[6]=bflo(a.w); g[7]=bfhi(a.w);
            g[8]=bflo(b4);  g[9]=bfhi(b4);
            float e[MN];
            #pragma unroll
            for (int j = 0; j < MN; ++j) e[j] = __expf(-g[j] * invreg);
            PL4x[r] = make_uint4(packbf(e[0],e[1]), packbf(e[2],e[3]),
                                 packbf(e[4],e[5]), packbf(e[6],e[7]));
            PL1x[r] = packbf(e[8], e[9]);
        }

        // ---- Sinkhorn iter 0 (u = 1) — only for cgi==0; else warm-start from prev v ----
        if (cgi == 0) {
            float a[MN];
            #pragma unroll
            for (int j = 0; j < MN; ++j) a[j] = 0.f;
            #pragma unroll
            for (int k = 0; k < RPT; ++k) {
                const int r = tid + k * TPB;
                uint4 q = PL4x[r]; unsigned b4 = PL1x[r];
                a[0]+=bflo(q.x); a[1]+=bfhi(q.x); a[2]+=bflo(q.y); a[3]+=bfhi(q.y);
                a[4]+=bflo(q.z); a[5]+=bfhi(q.z); a[6]+=bflo(q.w); a[7]+=bfhi(q.w);
                a[8]+=bflo(b4);  a[9]+=bfhi(b4);
            }
            #pragma unroll
            for (int p = 0; p < 5; ++p) sPp[tid * 7 + p] = packbf(a[2*p], a[2*p+1]);
            __syncthreads();
            if (tid < 320) {
                const int p = tid >> 6, c = tid & 63;
                float s0 = 0.f, s1 = 0.f;
                #pragma unroll
                for (int kk = 0; kk < NW; ++kk) {
                    unsigned w = sPp[(c + (kk << 6)) * 7 + p];
                    s0 += bflo(w); s1 += bfhi(w);
                }
                #pragma unroll
                for (int d = 32; d; d >>= 1) { s0 += __shfl_xor(s0, d); s1 += __shfl_xor(s1, d); }
                if (c == 0) {
                    float v0 = sq[2*p] / s0, v1 = sq[2*p+1] / s1;
                    svp[p] = packbf(v0, v1);
                    sVf[2*p] = v0; sVf[2*p+1] = v1;
                }
            }
            __syncthreads();
        }

        // ---- Sinkhorn fused (u,v) x50, early exit on v fixed point ----
        for (int it = 1; it <= NSK; ++it) {
            float vv[MN];
            #pragma unroll
            for (int p = 0; p < 5; ++p) {
                unsigned w = svp[p];
                vv[2*p] = bflo(w); vv[2*p+1] = bfhi(w);
            }
            float a[MN];
            #pragma unroll
            for (int j = 0; j < MN; ++j) a[j] = 0.f;
            #pragma unroll
            for (int k = 0; k < RPT; ++k) {
                const int r = tid + k * TPB;
                uint4 q = PL4x[r]; unsigned b4 = PL1x[r];
                float e[MN];
                e[0]=bflo(q.x); e[1]=bfhi(q.x); e[2]=bflo(q.y); e[3]=bfhi(q.y);
                e[4]=bflo(q.z); e[5]=bfhi(q.z); e[6]=bflo(q.w); e[7]=bfhi(q.w);
                e[8]=bflo(b4);  e[9]=bfhi(b4);
                float R = 0.f;
                #pragma unroll
                for (int j = 0; j < MN; ++j) R += e[j] * vv[j];
                const float u = invn * __builtin_amdgcn_rcpf(R);
                uu[k] = u;
                #pragma unroll
                for (int j = 0; j < MN; ++j) a[j] += e[j] * u;
            }
            #pragma unroll
            for (int p = 0; p < 5; ++p) sPp[tid * 7 + p] = packbf(a[2*p], a[2*p+1]);
            __syncthreads();
            if (tid < 320) {
                const int p = tid >> 6, c = tid & 63;
                float s0 = 0.f, s1 = 0.f;
                #pragma unroll
                for (int kk = 0; kk < NW; ++kk) {
                    unsigned w = sPp[(c + (kk << 6)) * 7 + p];
                    s0 += bflo(w); s1 += bfhi(w);
                }
                #pragma unroll
                for (int d = 32; d; d >>= 1) { s0 += __shfl_xor(s0, d); s1 += __shfl_xor(s1, d); }
                if (c == 0) {
                    float v0 = sq[2*p] / s0, v1 = sq[2*p+1] / s1;
                    float o0 = sVf[2*p],    o1 = sVf[2*p+1];
                    sCv[p] = (__builtin_fabsf(v0 - o0) <= 2e-4f * v0 &&
                              __builtin_fabsf(v1 - o1) <= 2e-4f * v1) ? 1.f : 0.f;
                    sVf[2*p] = v0; sVf[2*p+1] = v1;
                    svp[p] = packbf(v0, v1);
                }
            }
            __syncthreads();
            if (sCv[0] + sCv[1] + sCv[2] + sCv[3] + sCv[4] == 5.f) break;
        }

        // ---- dT phase: dd = u*E*v - T; dots; planes <- dd(bf16) ----
        {
            float vv[MN];
            #pragma unroll
            for (int p = 0; p < 5; ++p) {
                unsigned w = svp[p];
                vv[2*p] = bflo(w); vv[2*p+1] = bfhi(w);
            }
            float sMdT = 0.f, sCdT = 0.f, sCTdT = 0.f;
            #pragma unroll
            for (int k = 0; k < RPT; ++k) {
                const int r = tid + k * TPB;
                const float cp = (float)degi[r] * invn;
                const size_t b5 = (size_t)r * 5;
                const float u = uu[k];
                uint4 q = PL4x[r]; unsigned b4 = PL1x[r];
                float e[MN], dd[MN];
                e[0]=bflo(q.x); e[1]=bfhi(q.x); e[2]=bflo(q.y); e[3]=bfhi(q.y);
                e[4]=bflo(q.z); e[5]=bfhi(q.z); e[6]=bflo(q.w); e[7]=bfhi(q.w);
                e[8]=bflo(b4);  e[9]=bfhi(b4);
                #pragma unroll
                for (int h = 0; h < 5; ++h) {
                    unsigned tw = Tb[b5 + h], cw = Cb[b5 + h];
                    float2 mv = *(const float2*)(Mb + (size_t)r * MN + 2*h);
                    float d0 = u * e[2*h]   * vv[2*h]   - bflo(tw);
                    float d1 = u * e[2*h+1] * vv[2*h+1] - bfhi(tw);
                    dd[2*h] = d0; dd[2*h+1] = d1;
                    sMdT  += mv.x * d0 + mv.y * d1;
                    sCdT  += (cp + scq[2*h]) * d0 + (cp + scq[2*h+1]) * d1;
                    sCTdT += bflo(cw) * d0 + bfhi(cw) * d1;
                }
                PL4x[r] = make_uint4(packbf(dd[0],dd[1]), packbf(dd[2],dd[3]),
                                     packbf(dd[4],dd[5]), packbf(dd[6],dd[7]));
                PL1x[r] = packbf(dd[8], dd[9]);
            }
            #pragma unroll
            for (int d = 32; d; d >>= 1) {
                sMdT  += __shfl_xor(sMdT, d);
                sCdT  += __shfl_xor(sCdT, d);
                sCTdT += __shfl_xor(sCTdT, d);
            }
            if ((tid & 63) == 0) {
                const int w = tid >> 6;
                sRed[w] = sMdT; sRed[NW + w] = sCdT; sRed[2*NW + w] = sCTdT;
            }
            __syncthreads();   // dots staged AND dd planes visible block-wide
            if (tid == 0) {
                float r0 = 0.f, r1 = 0.f, r2 = 0.f;
                for (int w = 0; w < NW; ++w) { r0 += sRed[w]; r1 += sRed[NW+w]; r2 += sRed[2*NW+w]; }
                sDots[0] = r0; sDots[1] = r1; sDots[2] = r2;
            }
        }

        // ---- SpMM: D = C1 dT C2 (gather dd planes), sA = <D,dd>; Db <- bf16 ----
        {
            float dot = 0.f;
            #pragma unroll
            for (int k = 0; k < RPT; ++k) {
                const int r = tid + k * TPB;
                float y[MN];
                #pragma unroll
                for (int j = 0; j < MN; ++j) y[j] = 0.f;
                const int st = rowst[r], dg = degi[r];
                const unsigned short* cl = colix + st;
                for (int e = 0; e < dg; ++e) {
                    const int j = cl[e];
                    uint4 q = PL4x[j]; unsigned b4 = PL1x[j];
                    y[0] += bflo(q.x); y[1] += bfhi(q.x);
                    y[2] += bflo(q.y); y[3] += bfhi(q.y);
                    y[4] += bflo(q.z); y[5] += bfhi(q.z);
                    y[6] += bflo(q.w); y[7] += bfhi(q.w);
                    y[8] += bflo(b4);  y[9] += bfhi(b4);
                }
                uint4 q = PL4x[r]; unsigned b4 = PL1x[r];
                float dd[MN];
                dd[0]=bflo(q.x); dd[1]=bfhi(q.x); dd[2]=bflo(q.y); dd[3]=bfhi(q.y);
                dd[4]=bflo(q.z); dd[5]=bfhi(q.z); dd[6]=bflo(q.w); dd[7]=bfhi(q.w);
                dd[8]=bflo(b4);  dd[9]=bfhi(b4);
                #pragma unroll
                for (int h = 0; h < 5; ++h) {
                    float o0 = 0.f, o1 = 0.f;
                    #pragma unroll
                    for (int j = 0; j < MN; ++j) {
                        o0 += y[j] * sC2[j * MN + 2*h];
                        o1 += y[j] * sC2[j * MN + 2*h + 1];
                    }
                    dot += o0 * dd[2*h] + o1 * dd[2*h+1];
                    Db[(size_t)r * 5 + h] = packbf(o0, o1);
                }
            }
            #pragma unroll
            for (int d = 32; d; d >>= 1) dot += __shfl_xor(dot, d);
            if ((tid & 63) == 0) sRed[tid >> 6] = dot;
            __syncthreads();
            if (tid == 0) {
                float s = 0.f;
                for (int w = 0; w < NW; ++w) s += sRed[w];
                sDots[3] = s;
            }
            __syncthreads();
        }
    }

    // ---- F: final tau + objective (T,C,D from bf16 globals; dd from planes) ----
    if (tid == 0) {
        float a = -2.f * alpha * sDots[3];
        float b = oma * sDots[0] + alpha * (sDots[1] - 4.f * sDots[2]);
        float tau;
        if (a > 0.f) tau = fminf(fmaxf(-b / (2.f * a + 1e-16f), 0.f), 1.f);
        else         tau = (a + b < 0.f) ? 1.f : 0.f;
        sBC[0] = tau;
    }
    __syncthreads();
    {
        const float tau = sBC[0];
        float gw = 0.f, wass = 0.f;
        #pragma unroll
        for (int k = 0; k < RPT; ++k) {
            const int r = tid + k * TPB;
            const float cp = (float)degi[r] * invn;
            const size_t b5 = (size_t)r * 5;
            uint4 q = PL4x[r]; unsigned b4 = PL1x[r];
            float dd[MN];
            dd[0]=bflo(q.x); dd[1]=bfhi(q.x); dd[2]=bflo(q.y); dd[3]=bfhi(q.y);
            dd[4]=bflo(q.z); dd[5]=bfhi(q.z); dd[6]=bflo(q.w); dd[7]=bfhi(q.w);
            dd[8]=bflo(b4);  dd[9]=bfhi(b4);
            #pragma unroll
            for (int h = 0; h < 5; ++h) {
                unsigned tw = Tb[b5 + h], cw = Cb[b5 + h], Dw = Db[b5 + h];
                float2 mv = *(const float2*)(Mb + (size_t)r * MN + 2*h);
                float Tf0 = bflo(tw) + tau * dd[2*h];
                float Tf1 = bfhi(tw) + tau * dd[2*h+1];
                float Cf0 = bflo(cw) + tau * bflo(Dw);
                float Cf1 = bfhi(cw) + tau * bfhi(Dw);
                gw   += (cp + scq[2*h]   - 2.f * Cf0) * Tf0
                      + (cp + scq[2*h+1] - 2.f * Cf1) * Tf1;
                wass += mv.x * Tf0 + mv.y * Tf1;
            }
        }
        #pragma unroll
        for (int d = 32; d; d >>= 1) {
            gw   += __shfl_xor(gw, d);
            wass += __shfl_xor(wass, d);
        }
        if ((tid & 63) == 0) { sRed[tid >> 6] = gw; sRed[NW + (tid >> 6)] = wass; }
        __syncthreads();
        if (tid == 0) {
            float g = 0.f, ws = 0.f;
            for (int w = 0; w < NW; ++w) { g += sRed[w]; ws += sRed[NW + w]; }
            out[t] = oma * ws + alpha * g;
        }
    }
}

extern "C" void kernel_launch(void* const* d_in, const int* in_sizes, int n_in,
                              void* d_out, int out_size, void* d_ws, size_t ws_size,
                              hipStream_t stream) {
    const float* x   = (const float*)d_in[0];
    const void*  ei  = d_in[1];
    const float* tpl = (const float*)d_in[2];
    const float* tfp = (const float*)d_in[3];
    const float* q0  = (const float*)d_in[4];
    const float* a0  = (const float*)d_in[5];
    float* outp = (float*)d_out;
    float* Wp   = (float*)d_ws;
    (void)hipFuncSetAttribute(reinterpret_cast<const void*>(&tfgw_kernel),
                              hipFuncAttributeMaxDynamicSharedMemorySize, LDS_DYN);
    void* args[] = { &x, &ei, &tpl, &tfp, &q0, &a0, &outp, &Wp };
    hipLaunchCooperativeKernel(reinterpret_cast<const void*>(&tfgw_kernel),
                               dim3(NBLK), dim3(TPB), args, LDS_DYN, stream);
}